// Round 3
// baseline (1472.664 us; speedup 1.0000x reference)
//
#include <hip/hip_runtime.h>
#include <cstdint>
#include <cstddef>

// Problem constants (B,N,M,D fixed by the reference setup_inputs)
#define BB 8
#define NPTS 2048
#define DIM 64

typedef _Float16 f16x8 __attribute__((ext_vector_type(8)));
typedef float f32x4 __attribute__((ext_vector_type(4)));

// eps schedule: DIAMETER^2 * 0.25^k down to blur^2 = 0.0025 (9 entries)
static const float EPS_H[9] = {100.0f, 25.0f, 6.25f, 1.5625f, 0.390625f,
                               0.09765625f, 0.0244140625f, 0.006103515625f,
                               0.0025f};

struct SMTask {
  const _Float16* P;   // [B,2048,64] row-side points (output indexed by these)
  const _Float16* Q;   // [B,2048,64] reduce-side points
  const float* logw;   // [B,2048] log weights of Q side
  const float* pot;    // [B,2048] potential on Q side (nullptr at init)
  const float* qsq;    // [B,2048] |q|^2
  const float* psq;    // [B,2048] |p|^2
  const float* oldf;   // [B,2048] for 0.5*(old+new) averaging (nullptr = none)
  float* out;          // [B,2048]
};

// ---------------- prep kernels ----------------

__global__ __launch_bounds__(256) void norm_weights_k(
    const float* __restrict__ w, float* __restrict__ aout,
    float* __restrict__ logout, int n) {
  int b = blockIdx.x;
  const float* wb = w + (size_t)b * n;
  __shared__ float red[256];
  float s = 0.f;
  for (int i = threadIdx.x; i < n; i += 256) s += wb[i];
  red[threadIdx.x] = s;
  __syncthreads();
  for (int st = 128; st > 0; st >>= 1) {
    if (threadIdx.x < st) red[threadIdx.x] += red[threadIdx.x + st];
    __syncthreads();
  }
  float mass = red[0];
  if (mass == 0.f) mass = 1.f;
  float inv = 1.f / mass;
  for (int i = threadIdx.x; i < n; i += 256) {
    float av = wb[i] * inv;
    aout[(size_t)b * n + i] = av;
    logout[(size_t)b * n + i] = logf(av);
  }
}

// squared norm of each D=64 row + fp16 conversion: one wave per row
__global__ __launch_bounds__(256) void sqnorm_cvt_k(
    const float* __restrict__ X, float* __restrict__ sq,
    _Float16* __restrict__ Xh, int rows) {
  int row = blockIdx.x * 4 + (threadIdx.x >> 6);
  int lane = threadIdx.x & 63;
  if (row >= rows) return;
  float v = X[(size_t)row * DIM + lane];
  Xh[(size_t)row * DIM + lane] = (_Float16)v;
  float s = v * v;
  #pragma unroll
  for (int off = 32; off > 0; off >>= 1) s += __shfl_xor(s, off);
  if (lane == 0) sq[row] = s;
}

// ---------------- fused cost+softmin ----------------
// out[b,r] = -eps*ln2*( log2 sum_m 2^{ hq2[m] + S[r,m]*ie2 } ) + 0.5*psq[r]
// where S[r,m] = dot(P_r, Q_m) (f16 MFMA, fp32 acc),
// hq2[m] = (logw[m] + pot[m]/eps - 0.5*qsq[m]/eps)*log2e, ie2 = log2e/eps.
// Block: 4 waves on one 16-row tile; each wave sweeps 512 of the 2048 cols.
__global__ __launch_bounds__(256) void fused_softmin_k(
    SMTask t0, SMTask t1, SMTask t2, SMTask t3, float ie2, float neg_eps_ln2) {
  __shared__ float hq[NPTS];
  __shared__ float rmx[4][16];
  __shared__ float rs[4][16];
  SMTask T = (blockIdx.z == 0) ? t0
           : (blockIdx.z == 1) ? t1
           : (blockIdx.z == 2) ? t2 : t3;
  const int b = blockIdx.y;
  const int tid = threadIdx.x;
  const float LOG2E = 1.4426950408889634f;
  {
    const float* lw = T.logw + (size_t)b * NPTS;
    const float* q2 = T.qsq + (size_t)b * NPTS;
    const float* pt = T.pot ? T.pot + (size_t)b * NPTS : nullptr;
    for (int m = tid; m < NPTS; m += 256) {
      float h = fmaf(lw[m], LOG2E, -0.5f * q2[m] * ie2);
      if (pt) h = fmaf(pt[m], ie2, h);
      hq[m] = h;
    }
  }
  __syncthreads();

  const int lane = tid & 63, wave = tid >> 6;
  const int fr = lane & 15;       // A row / B col within tile; D col (m) index
  const int fkg = (lane >> 4) * 8;  // k-offset group
  const int r0 = blockIdx.x * 16;
  const _Float16* Pb = T.P + ((size_t)b * NPTS + r0) * DIM;
  const _Float16* Qb = T.Q + (size_t)b * NPTS * DIM;
  // A fragments: rows r0..r0+15, K=64 split into two K=32 chunks
  f16x8 a0 = *(const f16x8*)(Pb + fr * DIM + fkg);
  f16x8 a1 = *(const f16x8*)(Pb + fr * DIM + fkg + 32);

  float mx[4] = {-3e38f, -3e38f, -3e38f, -3e38f};
  float sm[4] = {0.f, 0.f, 0.f, 0.f};
  const int mbase = wave * (NPTS / 4);
  #pragma unroll 2
  for (int c = 0; c < NPTS / 4 / 16; ++c) {
    int m0 = mbase + c * 16;
    const _Float16* qrow = Qb + (size_t)(m0 + fr) * DIM + fkg;
    f16x8 b0 = *(const f16x8*)(qrow);
    f16x8 b1 = *(const f16x8*)(qrow + 32);
    f32x4 acc = {0.f, 0.f, 0.f, 0.f};
    acc = __builtin_amdgcn_mfma_f32_16x16x32_f16(a0, b0, acc, 0, 0, 0);
    acc = __builtin_amdgcn_mfma_f32_16x16x32_f16(a1, b1, acc, 0, 0, 0);
    float h = hq[m0 + fr];  // this lane's col m = m0+fr
    #pragma unroll
    for (int q = 0; q < 4; ++q) {  // 4 rows r = r0 + (lane>>4)*4 + q
      float v = fmaf(acc[q], ie2, h);
      float nm = fmaxf(mx[q], v);
      sm[q] = sm[q] * exp2f(mx[q] - nm) + exp2f(v - nm);
      mx[q] = nm;
    }
  }
  // reduce (mx,sm) over the 16 cols held by lanes fr=0..15 (same row group)
  #pragma unroll
  for (int off = 1; off < 16; off <<= 1) {
    #pragma unroll
    for (int q = 0; q < 4; ++q) {
      float omx = __shfl_xor(mx[q], off);
      float os = __shfl_xor(sm[q], off);
      float nm = fmaxf(mx[q], omx);
      sm[q] = sm[q] * exp2f(mx[q] - nm) + os * exp2f(omx - nm);
      mx[q] = nm;
    }
  }
  if (fr == 0) {
    #pragma unroll
    for (int q = 0; q < 4; ++q) {
      int rl = (lane >> 4) * 4 + q;
      rmx[wave][rl] = mx[q];
      rs[wave][rl] = sm[q];
    }
  }
  __syncthreads();
  // combine the 4 waves' m-split partials; rows 0..15 by threads 0..15
  if (tid < 16) {
    float nm = fmaxf(fmaxf(rmx[0][tid], rmx[1][tid]),
                     fmaxf(rmx[2][tid], rmx[3][tid]));
    float ss = 0.f;
    #pragma unroll
    for (int w = 0; w < 4; ++w) ss += rs[w][tid] * exp2f(rmx[w][tid] - nm);
    size_t oi = (size_t)b * NPTS + r0 + tid;
    float f = neg_eps_ln2 * (__log2f(ss) + nm) + 0.5f * T.psq[oi];
    if (T.oldf) f = 0.5f * (T.oldf[oi] + f);
    T.out[oi] = f;
  }
}

// ---------------- epilogue ----------------
__global__ __launch_bounds__(256) void loss_k(
    const float* __restrict__ aW, const float* __restrict__ f_fin,
    const float* __restrict__ f_aa, const float* __restrict__ bW,
    const float* __restrict__ g_fin, const float* __restrict__ g_bb,
    float* __restrict__ out) {
  __shared__ float red[256];
  float s = 0.f;
  for (int i = threadIdx.x; i < BB * NPTS; i += 256)
    s += aW[i] * (f_fin[i] - f_aa[i]);
  for (int i = threadIdx.x; i < BB * NPTS; i += 256)
    s += bW[i] * (g_fin[i] - g_bb[i]);
  red[threadIdx.x] = s;
  __syncthreads();
  for (int st = 128; st > 0; st >>= 1) {
    if (threadIdx.x < st) red[threadIdx.x] += red[threadIdx.x + st];
    __syncthreads();
  }
  if (threadIdx.x == 0) out[0] = red[0] * (1.f / BB);
}

__global__ void write_val_k(float* out, float v) { out[0] = v; }

// ---------------- host ----------------

extern "C" void kernel_launch(void* const* d_in, const int* in_sizes, int n_in,
                              void* d_out, int out_size, void* d_ws,
                              size_t ws_size, hipStream_t stream) {
  (void)in_sizes; (void)n_in; (void)out_size;
  const float* X = (const float*)d_in[0];   // [B,N,D]
  const float* Y = (const float*)d_in[1];   // [B,M,D]
  const float* W1 = (const float*)d_in[2];  // [B,N]
  const float* W2 = (const float*)d_in[3];  // [B,M]
  float* out = (float*)d_out;

  char* base = (char*)d_ws;
  size_t off = 0;
  auto alloc_b = [&](size_t bytes) {
    void* r = base + off;
    off += (bytes + 255) & ~(size_t)255;
    return r;
  };
  const size_t nP = (size_t)BB * NPTS;
  _Float16* Xh = (_Float16*)alloc_b(nP * DIM * 2);
  _Float16* Yh = (_Float16*)alloc_b(nP * DIM * 2);
  float* x2 = (float*)alloc_b(nP * 4);
  float* y2 = (float*)alloc_b(nP * 4);
  float* aW = (float*)alloc_b(nP * 4);
  float* bW = (float*)alloc_b(nP * 4);
  float* la = (float*)alloc_b(nP * 4);
  float* lb = (float*)alloc_b(nP * 4);
  float* fba[2] = {(float*)alloc_b(nP * 4), (float*)alloc_b(nP * 4)};
  float* gab[2] = {(float*)alloc_b(nP * 4), (float*)alloc_b(nP * 4)};
  float* faa[2] = {(float*)alloc_b(nP * 4), (float*)alloc_b(nP * 4)};
  float* gbb[2] = {(float*)alloc_b(nP * 4), (float*)alloc_b(nP * 4)};
  if (ws_size < off) {
    write_val_k<<<1, 1, 0, stream>>>(out, -(float)(ws_size >> 20));
    return;
  }

  // prep
  norm_weights_k<<<BB, 256, 0, stream>>>(W1, aW, la, NPTS);
  norm_weights_k<<<BB, 256, 0, stream>>>(W2, bW, lb, NPTS);
  sqnorm_cvt_k<<<BB * NPTS / 4, 256, 0, stream>>>(X, x2, Xh, BB * NPTS);
  sqnorm_cvt_k<<<BB * NPTS / 4, 256, 0, stream>>>(Y, y2, Yh, BB * NPTS);

  const float LN2 = 0.6931471805599453f;
  const float LOG2E = 1.4426950408889634f;
  dim3 fg(NPTS / 16, BB, 4);

  auto launch4 = [&](SMTask A, SMTask B2, SMTask C, SMTask D2, float eps) {
    float ie2 = LOG2E / eps;
    float nel = -eps * LN2;
    fused_softmin_k<<<fg, 256, 0, stream>>>(A, B2, C, D2, ie2, nel);
  };

  // init at eps0 (no potential, no averaging)
  {
    float e = EPS_H[0];
    launch4(
        // f_ba = softmin_y(Cxy, log b)
        SMTask{Xh, Yh, lb, nullptr, y2, x2, nullptr, fba[0]},
        // g_ab = softmin_x(Cyx, log a)
        SMTask{Yh, Xh, la, nullptr, x2, y2, nullptr, gab[0]},
        // f_aa = softmin_x(Cxx, log a)
        SMTask{Xh, Xh, la, nullptr, x2, x2, nullptr, faa[0]},
        // g_bb = softmin_y(Cyy, log b)
        SMTask{Yh, Yh, lb, nullptr, y2, y2, nullptr, gbb[0]},
        e);
  }

  // annealing loop: symmetric averaged updates, double-buffered
  int cur = 0;
  for (int it = 0; it < 9; ++it) {
    float e = EPS_H[it];
    int nxt = cur ^ 1;
    launch4(
        SMTask{Xh, Yh, lb, gab[cur], y2, x2, fba[cur], fba[nxt]},
        SMTask{Yh, Xh, la, fba[cur], x2, y2, gab[cur], gab[nxt]},
        SMTask{Xh, Xh, la, faa[cur], x2, x2, faa[cur], faa[nxt]},
        SMTask{Yh, Yh, lb, gbb[cur], y2, y2, gbb[cur], gbb[nxt]},
        e);
    cur = nxt;
  }

  // final extrapolation at eps target (no averaging)
  {
    float e = EPS_H[8];
    int nxt = cur ^ 1;
    launch4(
        SMTask{Xh, Yh, lb, gab[cur], y2, x2, nullptr, fba[nxt]},
        SMTask{Yh, Xh, la, fba[cur], x2, y2, nullptr, gab[nxt]},
        SMTask{Xh, Xh, la, faa[cur], x2, x2, nullptr, faa[nxt]},
        SMTask{Yh, Yh, lb, gbb[cur], y2, y2, nullptr, gbb[nxt]},
        e);
    loss_k<<<1, 256, 0, stream>>>(aW, fba[nxt], faa[nxt], bW, gab[nxt],
                                  gbb[nxt], out);
  }
}